// Round 10
// baseline (53.474 us; speedup 1.0000x reference)
//
#include <hip/hip_runtime.h>
#include <cfloat>
#include <cmath>

#define F_   8
#define H_   24
#define W_   24
#define NTOK 4608
#define NSEQ 4609
#define MPAD 4736           // 37*128 = 74*64
#define DIM  512
#define QKVC 1536           // q | k | v
#define NNB  28
#define SCALEF 0.125f

typedef unsigned short ushort_t;
typedef __attribute__((ext_vector_type(8))) short short8v;
typedef __attribute__((ext_vector_type(8))) unsigned short ushort8v;
typedef __attribute__((ext_vector_type(4))) float floatx4;

typedef const __attribute__((address_space(1))) unsigned int guint_t;
typedef __attribute__((address_space(3))) unsigned int luint_t;

__device__ __forceinline__ float bf2f(unsigned short u) {
    return __uint_as_float(((unsigned)u) << 16);
}
__device__ __forceinline__ unsigned short f2bf(float f) {
    unsigned u = __float_as_uint(f);
    unsigned r = (u + 0x7FFFu + ((u >> 16) & 1u)) >> 16;
    return (unsigned short)r;
}
// pack two f32 -> u32 of 2 bf16 (truncation) via one v_perm_b32
__device__ __forceinline__ unsigned pk2(float a, float b) {
    return __builtin_amdgcn_perm(__float_as_uint(b), __float_as_uint(a), 0x07060302u);
}

// ---------------------------------------------------------------------------
// Weight conversion only (x conversion fused into gemm_qkv staging):
//  blocks [0,192):   [w_q | w_kv] -> wcatT (bf16, [1536][512])
//  blocks [192,256): w_out -> woutT (bf16, [512][512])
// 64x64 LDS-tile transpose; coalesced f32 reads, coalesced ushort8 writes.
// ---------------------------------------------------------------------------
#define CONV_BLOCKS 256

__global__ __launch_bounds__(256) void conv_k(
    const float* __restrict__ wq, const float* __restrict__ wkv,
    const float* __restrict__ wout,
    ushort_t* __restrict__ wcatT, ushort_t* __restrict__ woutT)
{
    const int blk2 = blockIdx.x, tid = threadIdx.x;
    __shared__ ushort_t tile[64][72];

    const float* src; int ld, cb; ushort_t* dst; int k0;
    if (blk2 < 192) {
        int nt = blk2 >> 3, kt = blk2 & 7;
        int n0 = nt * 64;
        if (n0 < 512) { src = wq;  ld = 512;  cb = n0; }
        else          { src = wkv; ld = 1024; cb = n0 - 512; }
        dst = wcatT + (size_t)n0 * 512;
        k0 = kt * 64;
    } else {
        int b3 = blk2 - 192;
        int nt = b3 >> 3, kt = b3 & 7;
        src = wout; ld = 512; cb = nt * 64;
        dst = woutT + (size_t)(nt * 64) * 512;
        k0 = kt * 64;
    }

    {
        int r = tid >> 4, c4 = (tid & 15) * 4;
        #pragma unroll
        for (int p = 0; p < 4; ++p) {
            int rr = r + p * 16;
            float4 v = *reinterpret_cast<const float4*>(&src[(size_t)(k0 + rr) * ld + cb + c4]);
            tile[c4 + 0][rr] = f2bf(v.x);
            tile[c4 + 1][rr] = f2bf(v.y);
            tile[c4 + 2][rr] = f2bf(v.z);
            tile[c4 + 3][rr] = f2bf(v.w);
        }
    }
    __syncthreads();
    {
        int nl = tid >> 3, ks = (tid & 7) * 8;
        #pragma unroll
        for (int rep = 0; rep < 2; ++rep) {
            int nn = nl + rep * 32;
            ushort8v vv = *reinterpret_cast<const ushort8v*>(&tile[nn][ks]);
            *reinterpret_cast<ushort8v*>(&dst[(size_t)nn * 512 + k0 + ks]) = vv;
        }
    }
}

// ---------------------------------------------------------------------------
// bf16 MFMA GEMM, single-buffered: stage -> barrier -> compute -> barrier.
// BM=64 x 128 tile, BK=64, 4 waves, 16x16x32 MFMA, XOR slot swizzle,
// bijective XCD-chunked block swizzle, __launch_bounds__(256,4).
// F32A: A is f32 [NSEQ][512]; reg-staged with v_perm bf16-truncation pack
//       (fused x->bf16; rows >= NSEQ are zero). B async global_load_lds
//       issued FIRST so it flies during A reg-staging.
// else: A bf16 via async global_load_lds.
// ---------------------------------------------------------------------------
template<int BM, bool F32A, bool F32OUT>
__global__ __launch_bounds__(256, 4) void gemm_k(
    const void* __restrict__ Av,
    const ushort_t* __restrict__ BT,   // [N][512] bf16
    const float* __restrict__ bias,
    void* __restrict__ Cv, int ldc)
{
    __shared__ ushort_t sA[BM * 64];
    __shared__ ushort_t sB[128 * 64];
    const int tid = threadIdx.x;

    const int nwg = gridDim.x * gridDim.y;
    const int orig = blockIdx.y * gridDim.x + blockIdx.x;
    const int xcd = orig & 7;
    const int qq = nwg >> 3, rr8 = nwg & 7;
    const int wg = (xcd < rr8 ? xcd * (qq + 1) : rr8 * (qq + 1) + (xcd - rr8) * qq)
                   + (orig >> 3);
    const int row0 = (wg / gridDim.x) * BM;
    const int col0 = (wg % gridDim.x) * 128;

    const int wid = tid >> 6, lane = tid & 63;
    const int wr = wid >> 1, wc = wid & 1;
    const int l15 = lane & 15, kp = lane >> 4;
    constexpr int MR = BM / 32;        // m-fragments per wave

    floatx4 acc[MR][4];
    #pragma unroll
    for (int m = 0; m < MR; ++m)
        #pragma unroll
        for (int n = 0; n < 4; ++n)
            acc[m][n] = (floatx4){0.f, 0.f, 0.f, 0.f};

    const ushort_t* Ab = (const ushort_t*)Av;
    const float*    Af = (const float*)Av;
    const ushort_t* Bbase = BT + (size_t)col0 * 512;

    for (int kt = 0; kt < 8; ++kt) {
        const int k0 = kt * 64;
        // B first: async global->LDS, in flight during A staging
        #pragma unroll
        for (int rnd = 0; rnd < 4; ++rnd) {
            int r = rnd * 32 + (tid >> 3);
            int gs = (tid & 7) ^ (r & 7);
            __builtin_amdgcn_global_load_lds(
                (guint_t*)(Bbase + (size_t)r * 512 + k0 + gs * 8),
                (luint_t*)(sB + r * 64 + (tid & 7) * 8), 16, 0, 0);
        }
        if constexpr (F32A) {
            static_assert(BM == 64, "F32A staging assumes BM==64");
            int r = tid >> 2;                   // 0..63
            int kq = (tid & 3) << 4;            // 0,16,32,48
            float4 f0 = make_float4(0.f,0.f,0.f,0.f), f1 = f0, f2 = f0, f3 = f0;
            if (row0 + r < NSEQ) {
                const float* sp = Af + (size_t)(row0 + r) * 512 + k0 + kq;
                f0 = *(const float4*)(sp + 0);
                f1 = *(const float4*)(sp + 4);
                f2 = *(const float4*)(sp + 8);
                f3 = *(const float4*)(sp + 12);
            }
            uint4 lo, hi;
            lo.x = pk2(f0.x, f0.y); lo.y = pk2(f0.z, f0.w);
            lo.z = pk2(f1.x, f1.y); lo.w = pk2(f1.z, f1.w);
            hi.x = pk2(f2.x, f2.y); hi.y = pk2(f2.z, f2.w);
            hi.z = pk2(f3.x, f3.y); hi.w = pk2(f3.z, f3.w);
            int slot0 = kq >> 3;                // 0,2,4,6
            *(uint4*)&sA[r * 64 + ((slot0       ^ (r & 7)) << 3)] = lo;
            *(uint4*)&sA[r * 64 + (((slot0 | 1) ^ (r & 7)) << 3)] = hi;
        } else {
            #pragma unroll
            for (int rnd = 0; rnd < BM / 32; ++rnd) {
                int r = rnd * 32 + (tid >> 3);
                int gs = (tid & 7) ^ (r & 7);
                __builtin_amdgcn_global_load_lds(
                    (guint_t*)(Ab + (size_t)(row0 + r) * 512 + k0 + gs * 8),
                    (luint_t*)(sA + r * 64 + (tid & 7) * 8), 16, 0, 0);
            }
        }
        __syncthreads();

        #pragma unroll
        for (int kk = 0; kk < 2; ++kk) {
            short8v af[MR], bfr[4];
            #pragma unroll
            for (int m = 0; m < MR; ++m) {
                int r = wr * (BM / 2) + m * 16 + l15;
                int slot = kk * 4 + kp;
                af[m] = *(const short8v*)&sA[r * 64 + ((slot ^ (r & 7)) << 3)];
            }
            #pragma unroll
            for (int n = 0; n < 4; ++n) {
                int r = wc * 64 + n * 16 + l15;
                int slot = kk * 4 + kp;
                bfr[n] = *(const short8v*)&sB[r * 64 + ((slot ^ (r & 7)) << 3)];
            }
            #pragma unroll
            for (int m = 0; m < MR; ++m)
                #pragma unroll
                for (int n = 0; n < 4; ++n)
                    acc[m][n] = __builtin_amdgcn_mfma_f32_16x16x32_bf16(
                        af[m], bfr[n], acc[m][n], 0, 0, 0);
        }
        __syncthreads();
    }

    if (!F32OUT) {
        ushort_t* C = (ushort_t*)Cv;
        #pragma unroll
        for (int m = 0; m < MR; ++m) {
            int rb = row0 + wr * (BM / 2) + m * 16 + kp * 4;
            #pragma unroll
            for (int n = 0; n < 4; ++n) {
                int col = col0 + wc * 64 + n * 16 + l15;
                #pragma unroll
                for (int q = 0; q < 4; ++q)
                    C[(size_t)(rb + q) * ldc + col] = f2bf(acc[m][n][q]);
            }
        }
    } else {
        float* C = (float*)Cv;
        #pragma unroll
        for (int m = 0; m < MR; ++m) {
            int rb = row0 + wr * (BM / 2) + m * 16 + kp * 4;
            #pragma unroll
            for (int n = 0; n < 4; ++n) {
                int col = col0 + wc * 64 + n * 16 + l15;
                float bv = bias[col];
                #pragma unroll
                for (int q = 0; q < 4; ++q)
                    if (rb + q < NSEQ)
                        C[(size_t)(rb + q) * ldc + col] = acc[m][n][q] + bv;
            }
        }
    }
}

// ---------------------------------------------------------------------------
// Attention, wave-per-token (round-9 known-good): chunked batched K loads,
// V chunk-1 prefetch under softmax, hoisted PV broadcasts,
// __launch_bounds__(256,4), XCD-chunked block swizzle.
// ---------------------------------------------------------------------------
__global__ __launch_bounds__(256, 4) void attn_k(
    const ushort_t* __restrict__ qkv,
    const float* __restrict__ wtalk,
    ushort_t* __restrict__ outh)
{
    const int lane = threadIdx.x & 63;
    const int bid0 = blockIdx.x;                            // 1152 = 8*144
    const int bswz = (bid0 & 7) * (gridDim.x >> 3) + (bid0 >> 3);
    const int i = bswz * 4 + (threadIdx.x >> 6);
    const int h = lane >> 3, s = lane & 7;

    const int t = i / (H_ * W_), rem = i % (H_ * W_);
    const int yy = rem / W_, xx = rem % W_;

    int rowj = -1;
    if (lane == 0) rowj = 0;
    else if (lane < NNB) {
        int e = lane - 1;
        int dt = e / 9 - 1, dy = (e / 3) % 3 - 1, dx = e % 3 - 1;
        int nt = t + dt, ny = yy + dy, nx = xx + dx;
        bool valid = ((unsigned)nt < (unsigned)F_) && ((unsigned)ny < (unsigned)H_) &&
                     ((unsigned)nx < (unsigned)W_);
        int u = (nt * H_ + ny) * W_ + nx;
        rowj = (valid && u <= i) ? (u + 1) : -1;
    }

    // clamped row table for loads (masked -> row 0)
    int rows[NNB];
    #pragma unroll
    for (int j = 0; j < NNB; ++j) {
        int r = __shfl(rowj, j, 64);
        rows[j] = r < 0 ? 0 : r;
    }

    float qf[8];
    {
        ushort8v qv = *(const ushort8v*)&qkv[(size_t)(i + 1) * QKVC + lane * 8];
        #pragma unroll
        for (int e = 0; e < 8; ++e) qf[e] = bf2f(qv[e]);
    }

    // ---- K dots, chunked 12/12/4 (batched loads per chunk) ----
    float ps[NNB];
    {
        ushort8v kc[12];
        #pragma unroll
        for (int j = 0; j < 12; ++j)
            kc[j] = *(const ushort8v*)&qkv[(size_t)rows[j] * QKVC + 512 + lane * 8];
        #pragma unroll
        for (int j = 0; j < 12; ++j) {
            float a = 0.f;
            #pragma unroll
            for (int e = 0; e < 8; ++e) a += qf[e] * bf2f(kc[j][e]);
            ps[j] = a;
        }
        #pragma unroll
        for (int j = 12; j < 24; ++j)
            kc[j - 12] = *(const ushort8v*)&qkv[(size_t)rows[j] * QKVC + 512 + lane * 8];
        #pragma unroll
        for (int j = 12; j < 24; ++j) {
            float a = 0.f;
            #pragma unroll
            for (int e = 0; e < 8; ++e) a += qf[e] * bf2f(kc[j - 12][e]);
            ps[j] = a;
        }
        ushort8v kt_[4];
        #pragma unroll
        for (int j = 24; j < 28; ++j)
            kt_[j - 24] = *(const ushort8v*)&qkv[(size_t)rows[j] * QKVC + 512 + lane * 8];
        #pragma unroll
        for (int j = 24; j < 28; ++j) {
            float a = 0.f;
            #pragma unroll
            for (int e = 0; e < 8; ++e) a += qf[e] * bf2f(kt_[j - 24][e]);
            ps[j] = a;
        }
    }

    // ---- V chunk-1 prefetch: in flight across reduce/softmax/TH ----
    ushort8v vc[12];
    #pragma unroll
    for (int j = 0; j < 12; ++j)
        vc[j] = *(const ushort8v*)&qkv[(size_t)rows[j] * QKVC + 1024 + lane * 8];

    // ---- reduce-scatter (xor 1,2,4) ----
    float v1[14];
    {
        bool hi = (s & 1) != 0;
        #pragma unroll
        for (int m = 0; m < 14; ++m) {
            float keep = hi ? ps[2 * m + 1] : ps[2 * m];
            float oth  = hi ? ps[2 * m]     : ps[2 * m + 1];
            v1[m] = keep + __shfl_xor(oth, 1, 64);
        }
    }
    float v2[8];
    {
        bool hi = (s & 2) != 0;
        #pragma unroll
        for (int m = 0; m < 7; ++m) {
            float keep = hi ? v1[2 * m + 1] : v1[2 * m];
            float oth  = hi ? v1[2 * m]     : v1[2 * m + 1];
            v2[m] = keep + __shfl_xor(oth, 2, 64);
        }
        v2[7] = 0.f;
    }
    float simk[4];
    {
        bool hi = (s & 4) != 0;
        #pragma unroll
        for (int k = 0; k < 4; ++k) {
            float keep = hi ? v2[2 * k + 1] : v2[2 * k];
            float oth  = hi ? v2[2 * k]     : v2[2 * k + 1];
            simk[k] = keep + __shfl_xor(oth, 4, 64);
        }
    }
    #pragma unroll
    for (int k = 0; k < 4; ++k) {
        int j = s + 8 * k;
        int rj = __shfl(rowj, j, 64);
        simk[k] = (rj >= 0) ? simk[k] * SCALEF : -FLT_MAX;
    }

    // ---- softmax over the 8-lane x 4-slot group ----
    float mx = fmaxf(fmaxf(simk[0], simk[1]), fmaxf(simk[2], simk[3]));
    mx = fmaxf(mx, __shfl_xor(mx, 1, 64));
    mx = fmaxf(mx, __shfl_xor(mx, 2, 64));
    mx = fmaxf(mx, __shfl_xor(mx, 4, 64));
    float att[4];
    float S = 0.f;
    #pragma unroll
    for (int k = 0; k < 4; ++k) { att[k] = __expf(simk[k] - mx); S += att[k]; }
    S += __shfl_xor(S, 1, 64);
    S += __shfl_xor(S, 2, 64);
    S += __shfl_xor(S, 4, 64);
    float inv = 1.f / S;
    #pragma unroll
    for (int k = 0; k < 4; ++k) att[k] *= inv;

    // ---- talking heads ----
    float wtg[8];
    #pragma unroll
    for (int hh = 0; hh < 8; ++hh) wtg[hh] = wtalk[h * 8 + hh];
    float pk[4];
    #pragma unroll
    for (int k = 0; k < 4; ++k) {
        float acc = 0.f;
        #pragma unroll
        for (int hh = 0; hh < 8; ++hh)
            acc += wtg[hh] * __shfl(att[k], hh * 8 + s, 64);
        pk[k] = acc;
    }

    // hoisted PV broadcasts
    float pj[NNB];
    #pragma unroll
    for (int j = 0; j < NNB; ++j)
        pj[j] = __shfl(pk[j >> 3], h * 8 + (j & 7), 64);

    // ---- PV, chunked 12/12/4 ----
    float o[8];
    #pragma unroll
    for (int e = 0; e < 8; ++e) o[e] = 0.f;
    #pragma unroll
    for (int j = 0; j < 12; ++j) {
        #pragma unroll
        for (int e = 0; e < 8; ++e) o[e] += pj[j] * bf2f(vc[j][e]);
    }
    #pragma unroll
    for (int j = 12; j < 24; ++j)
        vc[j - 12] = *(const ushort8v*)&qkv[(size_t)rows[j] * QKVC + 1024 + lane * 8];
    #pragma unroll
    for (int j = 12; j < 24; ++j) {
        #pragma unroll
        for (int e = 0; e < 8; ++e) o[e] += pj[j] * bf2f(vc[j - 12][e]);
    }
    {
        ushort8v vt_[4];
        #pragma unroll
        for (int j = 24; j < 28; ++j)
            vt_[j - 24] = *(const ushort8v*)&qkv[(size_t)rows[j] * QKVC + 1024 + lane * 8];
        #pragma unroll
        for (int j = 24; j < 28; ++j) {
            #pragma unroll
            for (int e = 0; e < 8; ++e) o[e] += pj[j] * bf2f(vt_[j - 24][e]);
        }
    }

    ushort8v ov;
    #pragma unroll
    for (int e = 0; e < 8; ++e) ov[e] = f2bf(o[e]);
    *(ushort8v*)&outh[(size_t)(i + 1) * DIM + lane * 8] = ov;

    if (i == 0) {
        ushort8v bv = *(const ushort8v*)&qkv[1024 + lane * 8];
        *(ushort8v*)&outh[lane * 8] = bv;
    }
}

extern "C" void kernel_launch(void* const* d_in, const int* in_sizes, int n_in,
                              void* d_out, int out_size, void* d_ws, size_t ws_size,
                              hipStream_t stream) {
    const float* x     = (const float*)d_in[0];
    const float* wq    = (const float*)d_in[1];
    const float* wkv   = (const float*)d_in[2];
    const float* wtalk = (const float*)d_in[3];
    const float* wout  = (const float*)d_in[4];
    const float* bout  = (const float*)d_in[5];
    float* out = (float*)d_out;

    ushort_t* wcatT = (ushort_t*)d_ws;                    // 1536*512 bf16
    ushort_t* woutT = wcatT + (size_t)QKVC * 512;         // 512*512
    ushort_t* qkv   = woutT + (size_t)512 * 512;          // MPAD*1536
    ushort_t* outh  = qkv   + (size_t)MPAD * QKVC;        // MPAD*512

    dim3 blk(256);
    conv_k<<<CONV_BLOCKS, blk, 0, stream>>>(wq, wkv, wout, wcatT, woutT);
    gemm_k<64, true, false><<<dim3(12, 74), blk, 0, stream>>>(x, wcatT, nullptr, qkv, QKVC);
    attn_k<<<dim3(NTOK / 4), blk, 0, stream>>>(qkv, wtalk, outh);
    gemm_k<64, false, true><<<dim3(4, 74), blk, 0, stream>>>(outh, woutT, bout, out, DIM);
}

// Round 11
// 52.563 us; speedup vs baseline: 1.0173x; 1.0173x over previous
//
#include <hip/hip_runtime.h>
#include <cfloat>
#include <cmath>

#define F_   8
#define H_   24
#define W_   24
#define NTOK 4608
#define NSEQ 4609
#define MPAD 4736           // 37*128 = 74*64
#define DIM  512
#define QKVC 1536           // q | k | v
#define NNB  28
#define SCALEF 0.125f

typedef unsigned short ushort_t;
typedef __attribute__((ext_vector_type(8))) short short8v;
typedef __attribute__((ext_vector_type(8))) unsigned short ushort8v;
typedef __attribute__((ext_vector_type(4))) float floatx4;

typedef const __attribute__((address_space(1))) unsigned int guint_t;
typedef __attribute__((address_space(3))) unsigned int luint_t;

__device__ __forceinline__ float bf2f(unsigned short u) {
    return __uint_as_float(((unsigned)u) << 16);
}
__device__ __forceinline__ unsigned short f2bf(float f) {
    unsigned u = __float_as_uint(f);
    unsigned r = (u + 0x7FFFu + ((u >> 16) & 1u)) >> 16;
    return (unsigned short)r;
}

// ---------------------------------------------------------------------------
// Fused conversion (round-9 known-good):
//  blocks [0, XBLK):        x(f32) -> xb(bf16), rows zero-padded to MPAD
//  blocks [XBLK, XBLK+192): [w_q | w_kv] -> wcatT (bf16, [1536][512])
//  blocks [XBLK+192, +64):  w_out -> woutT (bf16, [512][512])
// ---------------------------------------------------------------------------
#define XBLK 1184                      // MPAD*512/2048
#define CONV_BLOCKS (XBLK + 192 + 64)

__global__ __launch_bounds__(256) void conv_k(
    const float* __restrict__ x, const float* __restrict__ wq,
    const float* __restrict__ wkv, const float* __restrict__ wout,
    ushort_t* __restrict__ xb, ushort_t* __restrict__ wcatT,
    ushort_t* __restrict__ woutT)
{
    const int bid = blockIdx.x, tid = threadIdx.x;
    __shared__ ushort_t tile[64][72];

    if (bid < XBLK) {
        int e0 = (bid * 256 + tid) * 8;
        int row = e0 >> 9;
        float4 a = make_float4(0.f, 0.f, 0.f, 0.f);
        float4 b = make_float4(0.f, 0.f, 0.f, 0.f);
        if (row < NSEQ) {
            a = *reinterpret_cast<const float4*>(&x[e0]);
            b = *reinterpret_cast<const float4*>(&x[e0 + 4]);
        }
        ushort8v o;
        o[0] = f2bf(a.x); o[1] = f2bf(a.y); o[2] = f2bf(a.z); o[3] = f2bf(a.w);
        o[4] = f2bf(b.x); o[5] = f2bf(b.y); o[6] = f2bf(b.z); o[7] = f2bf(b.w);
        *reinterpret_cast<ushort8v*>(&xb[e0]) = o;
        return;
    }

    int blk2 = bid - XBLK;
    const float* src; int ld, cb; ushort_t* dst; int k0;
    if (blk2 < 192) {
        int nt = blk2 >> 3, kt = blk2 & 7;
        int n0 = nt * 64;
        if (n0 < 512) { src = wq;  ld = 512;  cb = n0; }
        else          { src = wkv; ld = 1024; cb = n0 - 512; }
        dst = wcatT + (size_t)n0 * 512;
        k0 = kt * 64;
    } else {
        int b3 = blk2 - 192;
        int nt = b3 >> 3, kt = b3 & 7;
        src = wout; ld = 512; cb = nt * 64;
        dst = woutT + (size_t)(nt * 64) * 512;
        k0 = kt * 64;
    }

    {
        int r = tid >> 4, c4 = (tid & 15) * 4;
        #pragma unroll
        for (int p = 0; p < 4; ++p) {
            int rr = r + p * 16;
            float4 v = *reinterpret_cast<const float4*>(&src[(size_t)(k0 + rr) * ld + cb + c4]);
            tile[c4 + 0][rr] = f2bf(v.x);
            tile[c4 + 1][rr] = f2bf(v.y);
            tile[c4 + 2][rr] = f2bf(v.z);
            tile[c4 + 3][rr] = f2bf(v.w);
        }
    }
    __syncthreads();
    {
        int nl = tid >> 3, ks = (tid & 7) * 8;
        #pragma unroll
        for (int rep = 0; rep < 2; ++rep) {
            int nn = nl + rep * 32;
            ushort8v vv = *reinterpret_cast<const ushort8v*>(&tile[nn][ks]);
            *reinterpret_cast<ushort8v*>(&dst[(size_t)nn * 512 + k0 + ks]) = vv;
        }
    }
}

// ---------------------------------------------------------------------------
// bf16 MFMA GEMM, 2-phase double-buffered at BM=64 (48 KB LDS -> 3 blocks/CU,
// matching the 3.5-blocks/CU grid; round-5's structure, which failed only at
// BM=128/2-blocks/CU):
//   prologue: STAGE(0,0); vmcnt(0); barrier
//   iter kt<7: STAGE(cur^1, kt+1); COMPUTE(cur); vmcnt(0); barrier; swap
//   epilogue: COMPUTE(cur)
// Prefetch latency hides under the MFMA phase; barrier drain is only the
// already-mostly-landed prefetch. XOR slot swizzle, XCD-chunked block
// swizzle, __launch_bounds__(256,3).
// ---------------------------------------------------------------------------
template<int BM, bool F32OUT>
__global__ __launch_bounds__(256, 3) void gemm_k(
    const ushort_t* __restrict__ A,    // [MPAD][512] bf16
    const ushort_t* __restrict__ BT,   // [N][512] bf16
    const float* __restrict__ bias,
    void* __restrict__ Cv, int ldc)
{
    __shared__ ushort_t sA[2][BM * 64];
    __shared__ ushort_t sB[2][128 * 64];
    const int tid = threadIdx.x;

    const int nwg = gridDim.x * gridDim.y;
    const int orig = blockIdx.y * gridDim.x + blockIdx.x;
    const int xcd = orig & 7;
    const int qq = nwg >> 3, rr8 = nwg & 7;
    const int wg = (xcd < rr8 ? xcd * (qq + 1) : rr8 * (qq + 1) + (xcd - rr8) * qq)
                   + (orig >> 3);
    const int row0 = (wg / gridDim.x) * BM;
    const int col0 = (wg % gridDim.x) * 128;

    const int wid = tid >> 6, lane = tid & 63;
    const int wr = wid >> 1, wc = wid & 1;
    const int l15 = lane & 15, kp = lane >> 4;
    constexpr int MR = BM / 32;        // m-fragments per wave

    floatx4 acc[MR][4];
    #pragma unroll
    for (int m = 0; m < MR; ++m)
        #pragma unroll
        for (int n = 0; n < 4; ++n)
            acc[m][n] = (floatx4){0.f, 0.f, 0.f, 0.f};

    const ushort_t* Abase = A + (size_t)row0 * 512;
    const ushort_t* Bbase = BT + (size_t)col0 * 512;

    auto STAGE = [&](int buf, int kt) {
        const int k0 = kt * 64;
        #pragma unroll
        for (int rnd = 0; rnd < BM / 32; ++rnd) {
            int r = rnd * 32 + (tid >> 3);
            int gs = (tid & 7) ^ (r & 7);
            __builtin_amdgcn_global_load_lds(
                (guint_t*)(Abase + (size_t)r * 512 + k0 + gs * 8),
                (luint_t*)(&sA[buf][r * 64 + (tid & 7) * 8]), 16, 0, 0);
        }
        #pragma unroll
        for (int rnd = 0; rnd < 4; ++rnd) {
            int r = rnd * 32 + (tid >> 3);
            int gs = (tid & 7) ^ (r & 7);
            __builtin_amdgcn_global_load_lds(
                (guint_t*)(Bbase + (size_t)r * 512 + k0 + gs * 8),
                (luint_t*)(&sB[buf][r * 64 + (tid & 7) * 8]), 16, 0, 0);
        }
    };

    auto COMPUTE = [&](int buf) {
        #pragma unroll
        for (int kk = 0; kk < 2; ++kk) {
            short8v af[MR], bfr[4];
            #pragma unroll
            for (int m = 0; m < MR; ++m) {
                int r = wr * (BM / 2) + m * 16 + l15;
                int slot = kk * 4 + kp;
                af[m] = *(const short8v*)&sA[buf][r * 64 + ((slot ^ (r & 7)) << 3)];
            }
            #pragma unroll
            for (int n = 0; n < 4; ++n) {
                int r = wc * 64 + n * 16 + l15;
                int slot = kk * 4 + kp;
                bfr[n] = *(const short8v*)&sB[buf][r * 64 + ((slot ^ (r & 7)) << 3)];
            }
            #pragma unroll
            for (int m = 0; m < MR; ++m)
                #pragma unroll
                for (int n = 0; n < 4; ++n)
                    acc[m][n] = __builtin_amdgcn_mfma_f32_16x16x32_bf16(
                        af[m], bfr[n], acc[m][n], 0, 0, 0);
        }
    };

    STAGE(0, 0);
    asm volatile("s_waitcnt vmcnt(0)" ::: "memory");
    __builtin_amdgcn_s_barrier();
    int cur = 0;
    #pragma unroll 1
    for (int kt = 0; kt < 7; ++kt) {
        STAGE(cur ^ 1, kt + 1);        // prefetch next tile (in flight)
        COMPUTE(cur);                  // MFMA hides prefetch latency
        asm volatile("s_waitcnt vmcnt(0)" ::: "memory");
        __builtin_amdgcn_s_barrier();
        cur ^= 1;
    }
    COMPUTE(cur);

    if (!F32OUT) {
        ushort_t* C = (ushort_t*)Cv;
        #pragma unroll
        for (int m = 0; m < MR; ++m) {
            int rb = row0 + wr * (BM / 2) + m * 16 + kp * 4;
            #pragma unroll
            for (int n = 0; n < 4; ++n) {
                int col = col0 + wc * 64 + n * 16 + l15;
                #pragma unroll
                for (int q = 0; q < 4; ++q)
                    C[(size_t)(rb + q) * ldc + col] = f2bf(acc[m][n][q]);
            }
        }
    } else {
        float* C = (float*)Cv;
        #pragma unroll
        for (int m = 0; m < MR; ++m) {
            int rb = row0 + wr * (BM / 2) + m * 16 + kp * 4;
            #pragma unroll
            for (int n = 0; n < 4; ++n) {
                int col = col0 + wc * 64 + n * 16 + l15;
                float bv = bias[col];
                #pragma unroll
                for (int q = 0; q < 4; ++q)
                    if (rb + q < NSEQ)
                        C[(size_t)(rb + q) * ldc + col] = acc[m][n][q] + bv;
            }
        }
    }
}

// ---------------------------------------------------------------------------
// Attention, wave-per-token (round-9 known-good): chunked batched K loads,
// V chunk-1 prefetch under softmax, hoisted PV broadcasts,
// __launch_bounds__(256,4), XCD-chunked block swizzle.
// ---------------------------------------------------------------------------
__global__ __launch_bounds__(256, 4) void attn_k(
    const ushort_t* __restrict__ qkv,
    const float* __restrict__ wtalk,
    ushort_t* __restrict__ outh)
{
    const int lane = threadIdx.x & 63;
    const int bid0 = blockIdx.x;                            // 1152 = 8*144
    const int bswz = (bid0 & 7) * (gridDim.x >> 3) + (bid0 >> 3);
    const int i = bswz * 4 + (threadIdx.x >> 6);
    const int h = lane >> 3, s = lane & 7;

    const int t = i / (H_ * W_), rem = i % (H_ * W_);
    const int yy = rem / W_, xx = rem % W_;

    int rowj = -1;
    if (lane == 0) rowj = 0;
    else if (lane < NNB) {
        int e = lane - 1;
        int dt = e / 9 - 1, dy = (e / 3) % 3 - 1, dx = e % 3 - 1;
        int nt = t + dt, ny = yy + dy, nx = xx + dx;
        bool valid = ((unsigned)nt < (unsigned)F_) && ((unsigned)ny < (unsigned)H_) &&
                     ((unsigned)nx < (unsigned)W_);
        int u = (nt * H_ + ny) * W_ + nx;
        rowj = (valid && u <= i) ? (u + 1) : -1;
    }

    // clamped row table for loads (masked -> row 0)
    int rows[NNB];
    #pragma unroll
    for (int j = 0; j < NNB; ++j) {
        int r = __shfl(rowj, j, 64);
        rows[j] = r < 0 ? 0 : r;
    }

    float qf[8];
    {
        ushort8v qv = *(const ushort8v*)&qkv[(size_t)(i + 1) * QKVC + lane * 8];
        #pragma unroll
        for (int e = 0; e < 8; ++e) qf[e] = bf2f(qv[e]);
    }

    // ---- K dots, chunked 12/12/4 (batched loads per chunk) ----
    float ps[NNB];
    {
        ushort8v kc[12];
        #pragma unroll
        for (int j = 0; j < 12; ++j)
            kc[j] = *(const ushort8v*)&qkv[(size_t)rows[j] * QKVC + 512 + lane * 8];
        #pragma unroll
        for (int j = 0; j < 12; ++j) {
            float a = 0.f;
            #pragma unroll
            for (int e = 0; e < 8; ++e) a += qf[e] * bf2f(kc[j][e]);
            ps[j] = a;
        }
        #pragma unroll
        for (int j = 12; j < 24; ++j)
            kc[j - 12] = *(const ushort8v*)&qkv[(size_t)rows[j] * QKVC + 512 + lane * 8];
        #pragma unroll
        for (int j = 12; j < 24; ++j) {
            float a = 0.f;
            #pragma unroll
            for (int e = 0; e < 8; ++e) a += qf[e] * bf2f(kc[j - 12][e]);
            ps[j] = a;
        }
        ushort8v kt_[4];
        #pragma unroll
        for (int j = 24; j < 28; ++j)
            kt_[j - 24] = *(const ushort8v*)&qkv[(size_t)rows[j] * QKVC + 512 + lane * 8];
        #pragma unroll
        for (int j = 24; j < 28; ++j) {
            float a = 0.f;
            #pragma unroll
            for (int e = 0; e < 8; ++e) a += qf[e] * bf2f(kt_[j - 24][e]);
            ps[j] = a;
        }
    }

    // ---- V chunk-1 prefetch: in flight across reduce/softmax/TH ----
    ushort8v vc[12];
    #pragma unroll
    for (int j = 0; j < 12; ++j)
        vc[j] = *(const ushort8v*)&qkv[(size_t)rows[j] * QKVC + 1024 + lane * 8];

    // ---- reduce-scatter (xor 1,2,4) ----
    float v1[14];
    {
        bool hi = (s & 1) != 0;
        #pragma unroll
        for (int m = 0; m < 14; ++m) {
            float keep = hi ? ps[2 * m + 1] : ps[2 * m];
            float oth  = hi ? ps[2 * m]     : ps[2 * m + 1];
            v1[m] = keep + __shfl_xor(oth, 1, 64);
        }
    }
    float v2[8];
    {
        bool hi = (s & 2) != 0;
        #pragma unroll
        for (int m = 0; m < 7; ++m) {
            float keep = hi ? v1[2 * m + 1] : v1[2 * m];
            float oth  = hi ? v1[2 * m]     : v1[2 * m + 1];
            v2[m] = keep + __shfl_xor(oth, 2, 64);
        }
        v2[7] = 0.f;
    }
    float simk[4];
    {
        bool hi = (s & 4) != 0;
        #pragma unroll
        for (int k = 0; k < 4; ++k) {
            float keep = hi ? v2[2 * k + 1] : v2[2 * k];
            float oth  = hi ? v2[2 * k]     : v2[2 * k + 1];
            simk[k] = keep + __shfl_xor(oth, 4, 64);
        }
    }
    #pragma unroll
    for (int k = 0; k < 4; ++k) {
        int j = s + 8 * k;
        int rj = __shfl(rowj, j, 64);
        simk[k] = (rj >= 0) ? simk[k] * SCALEF : -FLT_MAX;
    }

    // ---- softmax over the 8-lane x 4-slot group ----
    float mx = fmaxf(fmaxf(simk[0], simk[1]), fmaxf(simk[2], simk[3]));
    mx = fmaxf(mx, __shfl_xor(mx, 1, 64));
    mx = fmaxf(mx, __shfl_xor(mx, 2, 64));
    mx = fmaxf(mx, __shfl_xor(mx, 4, 64));
    float att[4];
    float S = 0.f;
    #pragma unroll
    for (int k = 0; k < 4; ++k) { att[k] = __expf(simk[k] - mx); S += att[k]; }
    S += __shfl_xor(S, 1, 64);
    S += __shfl_xor(S, 2, 64);
    S += __shfl_xor(S, 4, 64);
    float inv = 1.f / S;
    #pragma unroll
    for (int k = 0; k < 4; ++k) att[k] *= inv;

    // ---- talking heads ----
    float wtg[8];
    #pragma unroll
    for (int hh = 0; hh < 8; ++hh) wtg[hh] = wtalk[h * 8 + hh];
    float pk[4];
    #pragma unroll
    for (int k = 0; k < 4; ++k) {
        float acc = 0.f;
        #pragma unroll
        for (int hh = 0; hh < 8; ++hh)
            acc += wtg[hh] * __shfl(att[k], hh * 8 + s, 64);
        pk[k] = acc;
    }

    // hoisted PV broadcasts
    float pj[NNB];
    #pragma unroll
    for (int j = 0; j < NNB; ++j)
        pj[j] = __shfl(pk[j >> 3], h * 8 + (j & 7), 64);

    // ---- PV, chunked 12/12/4 ----
    float o[8];
    #pragma unroll
    for (int e = 0; e < 8; ++e) o[e] = 0.f;
    #pragma unroll
    for (int j = 0; j < 12; ++j) {
        #pragma unroll
        for (int e = 0; e < 8; ++e) o[e] += pj[j] * bf2f(vc[j][e]);
    }
    #pragma unroll
    for (int j = 12; j < 24; ++j)
        vc[j - 12] = *(const ushort8v*)&qkv[(size_t)rows[j] * QKVC + 1024 + lane * 8];
    #pragma unroll
    for (int j = 12; j < 24; ++j) {
        #pragma unroll
        for (int e = 0; e < 8; ++e) o[e] += pj[j] * bf2f(vc[j - 12][e]);
    }
    {
        ushort8v vt_[4];
        #pragma unroll
        for (int j = 24; j < 28; ++j)
            vt_[j - 24] = *(const ushort8v*)&qkv[(size_t)rows[j] * QKVC + 1024 + lane * 8];
        #pragma unroll
        for (int j = 24; j < 28; ++j) {
            #pragma unroll
            for (int e = 0; e < 8; ++e) o[e] += pj[j] * bf2f(vt_[j - 24][e]);
        }
    }

    ushort8v ov;
    #pragma unroll
    for (int e = 0; e < 8; ++e) ov[e] = f2bf(o[e]);
    *(ushort8v*)&outh[(size_t)(i + 1) * DIM + lane * 8] = ov;

    if (i == 0) {
        ushort8v bv = *(const ushort8v*)&qkv[1024 + lane * 8];
        *(ushort8v*)&outh[lane * 8] = bv;
    }
}

extern "C" void kernel_launch(void* const* d_in, const int* in_sizes, int n_in,
                              void* d_out, int out_size, void* d_ws, size_t ws_size,
                              hipStream_t stream) {
    const float* x     = (const float*)d_in[0];
    const float* wq    = (const float*)d_in[1];
    const float* wkv   = (const float*)d_in[2];
    const float* wtalk = (const float*)d_in[3];
    const float* wout  = (const float*)d_in[4];
    const float* bout  = (const float*)d_in[5];
    float* out = (float*)d_out;

    ushort_t* xb    = (ushort_t*)d_ws;                    // MPAD*512 bf16
    ushort_t* wcatT = xb    + (size_t)MPAD * 512;         // 1536*512
    ushort_t* woutT = wcatT + (size_t)QKVC * 512;         // 512*512
    ushort_t* qkv   = woutT + (size_t)512 * 512;          // MPAD*1536
    ushort_t* outh  = qkv   + (size_t)MPAD * QKVC;        // MPAD*512

    dim3 blk(256);
    conv_k<<<CONV_BLOCKS, blk, 0, stream>>>(x, wq, wkv, wout, xb, wcatT, woutT);
    gemm_k<64, false><<<dim3(12, 74), blk, 0, stream>>>(xb, wcatT, nullptr, qkv, QKVC);
    attn_k<<<dim3(NTOK / 4), blk, 0, stream>>>(qkv, wtalk, outh);
    gemm_k<64, true><<<dim3(4, 74), blk, 0, stream>>>(outh, woutT, bout, out, DIM);
}

// Round 12
// 46.506 us; speedup vs baseline: 1.1498x; 1.1302x over previous
//
#include <hip/hip_runtime.h>
#include <cfloat>
#include <cmath>

#define F_   8
#define H_   24
#define W_   24
#define NTOK 4608
#define NSEQ 4609
#define MPAD 4736           // 37*128 = 74*64
#define DIM  512
#define QKVC 1536           // q | k | v
#define NNB  28
#define SCALEF 0.125f

typedef unsigned short ushort_t;
typedef __attribute__((ext_vector_type(8))) short short8v;
typedef __attribute__((ext_vector_type(8))) unsigned short ushort8v;
typedef __attribute__((ext_vector_type(4))) float floatx4;

typedef const __attribute__((address_space(1))) unsigned int guint_t;
typedef __attribute__((address_space(3))) unsigned int luint_t;

__device__ __forceinline__ float bf2f(unsigned short u) {
    return __uint_as_float(((unsigned)u) << 16);
}
__device__ __forceinline__ unsigned short f2bf(float f) {
    unsigned u = __float_as_uint(f);
    unsigned r = (u + 0x7FFFu + ((u >> 16) & 1u)) >> 16;
    return (unsigned short)r;
}

// ---------------------------------------------------------------------------
// Fused conversion (round-9 known-good):
//  blocks [0, XBLK):        x(f32) -> xb(bf16), rows zero-padded to MPAD
//  blocks [XBLK, XBLK+192): [w_q | w_kv] -> wcatT (bf16, [1536][512])
//  blocks [XBLK+192, +64):  w_out -> woutT (bf16, [512][512])
// ---------------------------------------------------------------------------
#define XBLK 1184                      // MPAD*512/2048
#define CONV_BLOCKS (XBLK + 192 + 64)

__global__ __launch_bounds__(256) void conv_k(
    const float* __restrict__ x, const float* __restrict__ wq,
    const float* __restrict__ wkv, const float* __restrict__ wout,
    ushort_t* __restrict__ xb, ushort_t* __restrict__ wcatT,
    ushort_t* __restrict__ woutT)
{
    const int bid = blockIdx.x, tid = threadIdx.x;
    __shared__ ushort_t tile[64][72];

    if (bid < XBLK) {
        int e0 = (bid * 256 + tid) * 8;
        int row = e0 >> 9;
        float4 a = make_float4(0.f, 0.f, 0.f, 0.f);
        float4 b = make_float4(0.f, 0.f, 0.f, 0.f);
        if (row < NSEQ) {
            a = *reinterpret_cast<const float4*>(&x[e0]);
            b = *reinterpret_cast<const float4*>(&x[e0 + 4]);
        }
        ushort8v o;
        o[0] = f2bf(a.x); o[1] = f2bf(a.y); o[2] = f2bf(a.z); o[3] = f2bf(a.w);
        o[4] = f2bf(b.x); o[5] = f2bf(b.y); o[6] = f2bf(b.z); o[7] = f2bf(b.w);
        *reinterpret_cast<ushort8v*>(&xb[e0]) = o;
        return;
    }

    int blk2 = bid - XBLK;
    const float* src; int ld, cb; ushort_t* dst; int k0;
    if (blk2 < 192) {
        int nt = blk2 >> 3, kt = blk2 & 7;
        int n0 = nt * 64;
        if (n0 < 512) { src = wq;  ld = 512;  cb = n0; }
        else          { src = wkv; ld = 1024; cb = n0 - 512; }
        dst = wcatT + (size_t)n0 * 512;
        k0 = kt * 64;
    } else {
        int b3 = blk2 - 192;
        int nt = b3 >> 3, kt = b3 & 7;
        src = wout; ld = 512; cb = nt * 64;
        dst = woutT + (size_t)(nt * 64) * 512;
        k0 = kt * 64;
    }

    {
        int r = tid >> 4, c4 = (tid & 15) * 4;
        #pragma unroll
        for (int p = 0; p < 4; ++p) {
            int rr = r + p * 16;
            float4 v = *reinterpret_cast<const float4*>(&src[(size_t)(k0 + rr) * ld + cb + c4]);
            tile[c4 + 0][rr] = f2bf(v.x);
            tile[c4 + 1][rr] = f2bf(v.y);
            tile[c4 + 2][rr] = f2bf(v.z);
            tile[c4 + 3][rr] = f2bf(v.w);
        }
    }
    __syncthreads();
    {
        int nl = tid >> 3, ks = (tid & 7) * 8;
        #pragma unroll
        for (int rep = 0; rep < 2; ++rep) {
            int nn = nl + rep * 32;
            ushort8v vv = *reinterpret_cast<const ushort8v*>(&tile[nn][ks]);
            *reinterpret_cast<ushort8v*>(&dst[(size_t)nn * 512 + k0 + ks]) = vv;
        }
    }
}

// ---------------------------------------------------------------------------
// bf16 MFMA GEMM, single-buffered (round-9 structure, best-known):
//   stage(global_load_lds) -> __syncthreads -> compute -> __syncthreads
// Now templated on BN (128 or 64). Wave decomposition:
//   NWC = BN/64 wave-cols, NWR = 4/NWC wave-rows, WROWS = BM/NWR rows/wave,
//   MR = WROWS/16 m-fragments. Each wave covers WROWS x 64.
// BN=64 for gemm_out: 592 blocks (2.3/CU, 8 waves/CU) vs 296 (1.16/CU).
// XOR slot swizzle, bijective XCD-chunked block swizzle, launch_bounds(256,4).
// ---------------------------------------------------------------------------
template<int BM, int BN, bool F32OUT>
__global__ __launch_bounds__(256, 4) void gemm_k(
    const ushort_t* __restrict__ A,    // [MPAD][512] bf16
    const ushort_t* __restrict__ BT,   // [N][512] bf16
    const float* __restrict__ bias,
    void* __restrict__ Cv, int ldc)
{
    __shared__ ushort_t sA[BM * 64];
    __shared__ ushort_t sB[BN * 64];
    const int tid = threadIdx.x;

    const int nwg = gridDim.x * gridDim.y;
    const int orig = blockIdx.y * gridDim.x + blockIdx.x;
    const int xcd = orig & 7;
    const int qq = nwg >> 3, rr8 = nwg & 7;
    const int wg = (xcd < rr8 ? xcd * (qq + 1) : rr8 * (qq + 1) + (xcd - rr8) * qq)
                   + (orig >> 3);
    const int row0 = (wg / gridDim.x) * BM;
    const int col0 = (wg % gridDim.x) * BN;

    constexpr int NWC = BN / 64;       // wave-cols
    constexpr int NWR = 4 / NWC;       // wave-rows
    constexpr int WROWS = BM / NWR;    // rows per wave
    constexpr int MR = WROWS / 16;     // m-fragments per wave

    const int wid = tid >> 6, lane = tid & 63;
    const int wr = wid / NWC, wc = wid % NWC;
    const int l15 = lane & 15, kp = lane >> 4;

    floatx4 acc[MR][4];
    #pragma unroll
    for (int m = 0; m < MR; ++m)
        #pragma unroll
        for (int n = 0; n < 4; ++n)
            acc[m][n] = (floatx4){0.f, 0.f, 0.f, 0.f};

    const ushort_t* Abase = A + (size_t)row0 * 512;
    const ushort_t* Bbase = BT + (size_t)col0 * 512;

    for (int kt = 0; kt < 8; ++kt) {
        const int k0 = kt * 64;
        #pragma unroll
        for (int rnd = 0; rnd < BM / 32; ++rnd) {
            int r = rnd * 32 + (tid >> 3);
            int gs = (tid & 7) ^ (r & 7);
            __builtin_amdgcn_global_load_lds(
                (guint_t*)(Abase + (size_t)r * 512 + k0 + gs * 8),
                (luint_t*)(sA + r * 64 + (tid & 7) * 8), 16, 0, 0);
        }
        #pragma unroll
        for (int rnd = 0; rnd < BN / 32; ++rnd) {
            int r = rnd * 32 + (tid >> 3);
            int gs = (tid & 7) ^ (r & 7);
            __builtin_amdgcn_global_load_lds(
                (guint_t*)(Bbase + (size_t)r * 512 + k0 + gs * 8),
                (luint_t*)(sB + r * 64 + (tid & 7) * 8), 16, 0, 0);
        }
        __syncthreads();

        #pragma unroll
        for (int kk = 0; kk < 2; ++kk) {
            short8v af[MR], bfr[4];
            #pragma unroll
            for (int m = 0; m < MR; ++m) {
                int r = wr * WROWS + m * 16 + l15;
                int slot = kk * 4 + kp;
                af[m] = *(const short8v*)&sA[r * 64 + ((slot ^ (r & 7)) << 3)];
            }
            #pragma unroll
            for (int n = 0; n < 4; ++n) {
                int r = wc * 64 + n * 16 + l15;
                int slot = kk * 4 + kp;
                bfr[n] = *(const short8v*)&sB[r * 64 + ((slot ^ (r & 7)) << 3)];
            }
            #pragma unroll
            for (int m = 0; m < MR; ++m)
                #pragma unroll
                for (int n = 0; n < 4; ++n)
                    acc[m][n] = __builtin_amdgcn_mfma_f32_16x16x32_bf16(
                        af[m], bfr[n], acc[m][n], 0, 0, 0);
        }
        __syncthreads();
    }

    if (!F32OUT) {
        ushort_t* C = (ushort_t*)Cv;
        #pragma unroll
        for (int m = 0; m < MR; ++m) {
            int rb = row0 + wr * WROWS + m * 16 + kp * 4;
            #pragma unroll
            for (int n = 0; n < 4; ++n) {
                int col = col0 + wc * 64 + n * 16 + l15;
                #pragma unroll
                for (int q = 0; q < 4; ++q)
                    C[(size_t)(rb + q) * ldc + col] = f2bf(acc[m][n][q]);
            }
        }
    } else {
        float* C = (float*)Cv;
        #pragma unroll
        for (int m = 0; m < MR; ++m) {
            int rb = row0 + wr * WROWS + m * 16 + kp * 4;
            #pragma unroll
            for (int n = 0; n < 4; ++n) {
                int col = col0 + wc * 64 + n * 16 + l15;
                float bv = bias[col];
                #pragma unroll
                for (int q = 0; q < 4; ++q)
                    if (rb + q < NSEQ)
                        C[(size_t)(rb + q) * ldc + col] = acc[m][n][q] + bv;
            }
        }
    }
}

// ---------------------------------------------------------------------------
// Attention, wave-per-token (round-9 known-good): chunked batched K loads,
// V chunk-1 prefetch under softmax, hoisted PV broadcasts,
// __launch_bounds__(256,4), XCD-chunked block swizzle.
// ---------------------------------------------------------------------------
__global__ __launch_bounds__(256, 4) void attn_k(
    const ushort_t* __restrict__ qkv,
    const float* __restrict__ wtalk,
    ushort_t* __restrict__ outh)
{
    const int lane = threadIdx.x & 63;
    const int bid0 = blockIdx.x;                            // 1152 = 8*144
    const int bswz = (bid0 & 7) * (gridDim.x >> 3) + (bid0 >> 3);
    const int i = bswz * 4 + (threadIdx.x >> 6);
    const int h = lane >> 3, s = lane & 7;

    const int t = i / (H_ * W_), rem = i % (H_ * W_);
    const int yy = rem / W_, xx = rem % W_;

    int rowj = -1;
    if (lane == 0) rowj = 0;
    else if (lane < NNB) {
        int e = lane - 1;
        int dt = e / 9 - 1, dy = (e / 3) % 3 - 1, dx = e % 3 - 1;
        int nt = t + dt, ny = yy + dy, nx = xx + dx;
        bool valid = ((unsigned)nt < (unsigned)F_) && ((unsigned)ny < (unsigned)H_) &&
                     ((unsigned)nx < (unsigned)W_);
        int u = (nt * H_ + ny) * W_ + nx;
        rowj = (valid && u <= i) ? (u + 1) : -1;
    }

    // clamped row table for loads (masked -> row 0)
    int rows[NNB];
    #pragma unroll
    for (int j = 0; j < NNB; ++j) {
        int r = __shfl(rowj, j, 64);
        rows[j] = r < 0 ? 0 : r;
    }

    float qf[8];
    {
        ushort8v qv = *(const ushort8v*)&qkv[(size_t)(i + 1) * QKVC + lane * 8];
        #pragma unroll
        for (int e = 0; e < 8; ++e) qf[e] = bf2f(qv[e]);
    }

    // ---- K dots, chunked 12/12/4 (batched loads per chunk) ----
    float ps[NNB];
    {
        ushort8v kc[12];
        #pragma unroll
        for (int j = 0; j < 12; ++j)
            kc[j] = *(const ushort8v*)&qkv[(size_t)rows[j] * QKVC + 512 + lane * 8];
        #pragma unroll
        for (int j = 0; j < 12; ++j) {
            float a = 0.f;
            #pragma unroll
            for (int e = 0; e < 8; ++e) a += qf[e] * bf2f(kc[j][e]);
            ps[j] = a;
        }
        #pragma unroll
        for (int j = 12; j < 24; ++j)
            kc[j - 12] = *(const ushort8v*)&qkv[(size_t)rows[j] * QKVC + 512 + lane * 8];
        #pragma unroll
        for (int j = 12; j < 24; ++j) {
            float a = 0.f;
            #pragma unroll
            for (int e = 0; e < 8; ++e) a += qf[e] * bf2f(kc[j - 12][e]);
            ps[j] = a;
        }
        ushort8v kt_[4];
        #pragma unroll
        for (int j = 24; j < 28; ++j)
            kt_[j - 24] = *(const ushort8v*)&qkv[(size_t)rows[j] * QKVC + 512 + lane * 8];
        #pragma unroll
        for (int j = 24; j < 28; ++j) {
            float a = 0.f;
            #pragma unroll
            for (int e = 0; e < 8; ++e) a += qf[e] * bf2f(kt_[j - 24][e]);
            ps[j] = a;
        }
    }

    // ---- V chunk-1 prefetch: in flight across reduce/softmax/TH ----
    ushort8v vc[12];
    #pragma unroll
    for (int j = 0; j < 12; ++j)
        vc[j] = *(const ushort8v*)&qkv[(size_t)rows[j] * QKVC + 1024 + lane * 8];

    // ---- reduce-scatter (xor 1,2,4) ----
    float v1[14];
    {
        bool hi = (s & 1) != 0;
        #pragma unroll
        for (int m = 0; m < 14; ++m) {
            float keep = hi ? ps[2 * m + 1] : ps[2 * m];
            float oth  = hi ? ps[2 * m]     : ps[2 * m + 1];
            v1[m] = keep + __shfl_xor(oth, 1, 64);
        }
    }
    float v2[8];
    {
        bool hi = (s & 2) != 0;
        #pragma unroll
        for (int m = 0; m < 7; ++m) {
            float keep = hi ? v1[2 * m + 1] : v1[2 * m];
            float oth  = hi ? v1[2 * m]     : v1[2 * m + 1];
            v2[m] = keep + __shfl_xor(oth, 2, 64);
        }
        v2[7] = 0.f;
    }
    float simk[4];
    {
        bool hi = (s & 4) != 0;
        #pragma unroll
        for (int k = 0; k < 4; ++k) {
            float keep = hi ? v2[2 * k + 1] : v2[2 * k];
            float oth  = hi ? v2[2 * k]     : v2[2 * k + 1];
            simk[k] = keep + __shfl_xor(oth, 4, 64);
        }
    }
    #pragma unroll
    for (int k = 0; k < 4; ++k) {
        int j = s + 8 * k;
        int rj = __shfl(rowj, j, 64);
        simk[k] = (rj >= 0) ? simk[k] * SCALEF : -FLT_MAX;
    }

    // ---- softmax over the 8-lane x 4-slot group ----
    float mx = fmaxf(fmaxf(simk[0], simk[1]), fmaxf(simk[2], simk[3]));
    mx = fmaxf(mx, __shfl_xor(mx, 1, 64));
    mx = fmaxf(mx, __shfl_xor(mx, 2, 64));
    mx = fmaxf(mx, __shfl_xor(mx, 4, 64));
    float att[4];
    float S = 0.f;
    #pragma unroll
    for (int k = 0; k < 4; ++k) { att[k] = __expf(simk[k] - mx); S += att[k]; }
    S += __shfl_xor(S, 1, 64);
    S += __shfl_xor(S, 2, 64);
    S += __shfl_xor(S, 4, 64);
    float inv = 1.f / S;
    #pragma unroll
    for (int k = 0; k < 4; ++k) att[k] *= inv;

    // ---- talking heads ----
    float wtg[8];
    #pragma unroll
    for (int hh = 0; hh < 8; ++hh) wtg[hh] = wtalk[h * 8 + hh];
    float pk[4];
    #pragma unroll
    for (int k = 0; k < 4; ++k) {
        float acc = 0.f;
        #pragma unroll
        for (int hh = 0; hh < 8; ++hh)
            acc += wtg[hh] * __shfl(att[k], hh * 8 + s, 64);
        pk[k] = acc;
    }

    // hoisted PV broadcasts
    float pj[NNB];
    #pragma unroll
    for (int j = 0; j < NNB; ++j)
        pj[j] = __shfl(pk[j >> 3], h * 8 + (j & 7), 64);

    // ---- PV, chunked 12/12/4 ----
    float o[8];
    #pragma unroll
    for (int e = 0; e < 8; ++e) o[e] = 0.f;
    #pragma unroll
    for (int j = 0; j < 12; ++j) {
        #pragma unroll
        for (int e = 0; e < 8; ++e) o[e] += pj[j] * bf2f(vc[j][e]);
    }
    #pragma unroll
    for (int j = 12; j < 24; ++j)
        vc[j - 12] = *(const ushort8v*)&qkv[(size_t)rows[j] * QKVC + 1024 + lane * 8];
    #pragma unroll
    for (int j = 12; j < 24; ++j) {
        #pragma unroll
        for (int e = 0; e < 8; ++e) o[e] += pj[j] * bf2f(vc[j - 12][e]);
    }
    {
        ushort8v vt_[4];
        #pragma unroll
        for (int j = 24; j < 28; ++j)
            vt_[j - 24] = *(const ushort8v*)&qkv[(size_t)rows[j] * QKVC + 1024 + lane * 8];
        #pragma unroll
        for (int j = 24; j < 28; ++j) {
            #pragma unroll
            for (int e = 0; e < 8; ++e) o[e] += pj[j] * bf2f(vt_[j - 24][e]);
        }
    }

    ushort8v ov;
    #pragma unroll
    for (int e = 0; e < 8; ++e) ov[e] = f2bf(o[e]);
    *(ushort8v*)&outh[(size_t)(i + 1) * DIM + lane * 8] = ov;

    if (i == 0) {
        ushort8v bv = *(const ushort8v*)&qkv[1024 + lane * 8];
        *(ushort8v*)&outh[lane * 8] = bv;
    }
}

extern "C" void kernel_launch(void* const* d_in, const int* in_sizes, int n_in,
                              void* d_out, int out_size, void* d_ws, size_t ws_size,
                              hipStream_t stream) {
    const float* x     = (const float*)d_in[0];
    const float* wq    = (const float*)d_in[1];
    const float* wkv   = (const float*)d_in[2];
    const float* wtalk = (const float*)d_in[3];
    const float* wout  = (const float*)d_in[4];
    const float* bout  = (const float*)d_in[5];
    float* out = (float*)d_out;

    ushort_t* xb    = (ushort_t*)d_ws;                    // MPAD*512 bf16
    ushort_t* wcatT = xb    + (size_t)MPAD * 512;         // 1536*512
    ushort_t* woutT = wcatT + (size_t)QKVC * 512;         // 512*512
    ushort_t* qkv   = woutT + (size_t)512 * 512;          // MPAD*1536
    ushort_t* outh  = qkv   + (size_t)MPAD * QKVC;        // MPAD*512

    dim3 blk(256);
    conv_k<<<CONV_BLOCKS, blk, 0, stream>>>(x, wq, wkv, wout, xb, wcatT, woutT);
    gemm_k<64, 128, false><<<dim3(12, 74), blk, 0, stream>>>(xb, wcatT, nullptr, qkv, QKVC);
    attn_k<<<dim3(NTOK / 4), blk, 0, stream>>>(qkv, wtalk, outh);
    gemm_k<64, 64, true><<<dim3(8, 74), blk, 0, stream>>>(outh, woutT, bout, out, DIM);
}

// Round 13
// 46.023 us; speedup vs baseline: 1.1619x; 1.0105x over previous
//
#include <hip/hip_runtime.h>
#include <cfloat>
#include <cmath>

#define F_   8
#define H_   24
#define W_   24
#define NTOK 4608
#define NSEQ 4609
#define MPAD 4736           // 37*128 = 74*64
#define DIM  512
#define QKVC 1536           // q | k | v
#define NNB  28
#define SCALEF 0.125f

typedef unsigned short ushort_t;
typedef __attribute__((ext_vector_type(8))) short short8v;
typedef __attribute__((ext_vector_type(8))) unsigned short ushort8v;
typedef __attribute__((ext_vector_type(4))) float floatx4;
typedef __attribute__((ext_vector_type(2))) float floatx2;
typedef __attribute__((ext_vector_type(4))) unsigned int uint4v;

typedef const __attribute__((address_space(1))) unsigned int guint_t;
typedef __attribute__((address_space(3))) unsigned int luint_t;

__device__ __forceinline__ float bf2f(unsigned short u) {
    return __uint_as_float(((unsigned)u) << 16);
}
__device__ __forceinline__ unsigned short f2bf(float f) {
    unsigned u = __float_as_uint(f);
    unsigned r = (u + 0x7FFFu + ((u >> 16) & 1u)) >> 16;
    return (unsigned short)r;
}
// unpack u32 holding 2 bf16 (lo,hi) -> float2 {lo<<16, hi&0xffff0000}
__device__ __forceinline__ floatx2 up2(unsigned w) {
    floatx2 r;
    r.x = __uint_as_float(w << 16);
    r.y = __uint_as_float(w & 0xffff0000u);
    return r;
}

// ---------------------------------------------------------------------------
// Fused conversion (round-9 known-good):
//  blocks [0, XBLK):        x(f32) -> xb(bf16), rows zero-padded to MPAD
//  blocks [XBLK, XBLK+192): [w_q | w_kv] -> wcatT (bf16, [1536][512])
//  blocks [XBLK+192, +64):  w_out -> woutT (bf16, [512][512])
// ---------------------------------------------------------------------------
#define XBLK 1184                      // MPAD*512/2048
#define CONV_BLOCKS (XBLK + 192 + 64)

__global__ __launch_bounds__(256) void conv_k(
    const float* __restrict__ x, const float* __restrict__ wq,
    const float* __restrict__ wkv, const float* __restrict__ wout,
    ushort_t* __restrict__ xb, ushort_t* __restrict__ wcatT,
    ushort_t* __restrict__ woutT)
{
    const int bid = blockIdx.x, tid = threadIdx.x;
    __shared__ ushort_t tile[64][72];

    if (bid < XBLK) {
        int e0 = (bid * 256 + tid) * 8;
        int row = e0 >> 9;
        float4 a = make_float4(0.f, 0.f, 0.f, 0.f);
        float4 b = make_float4(0.f, 0.f, 0.f, 0.f);
        if (row < NSEQ) {
            a = *reinterpret_cast<const float4*>(&x[e0]);
            b = *reinterpret_cast<const float4*>(&x[e0 + 4]);
        }
        ushort8v o;
        o[0] = f2bf(a.x); o[1] = f2bf(a.y); o[2] = f2bf(a.z); o[3] = f2bf(a.w);
        o[4] = f2bf(b.x); o[5] = f2bf(b.y); o[6] = f2bf(b.z); o[7] = f2bf(b.w);
        *reinterpret_cast<ushort8v*>(&xb[e0]) = o;
        return;
    }

    int blk2 = bid - XBLK;
    const float* src; int ld, cb; ushort_t* dst; int k0;
    if (blk2 < 192) {
        int nt = blk2 >> 3, kt = blk2 & 7;
        int n0 = nt * 64;
        if (n0 < 512) { src = wq;  ld = 512;  cb = n0; }
        else          { src = wkv; ld = 1024; cb = n0 - 512; }
        dst = wcatT + (size_t)n0 * 512;
        k0 = kt * 64;
    } else {
        int b3 = blk2 - 192;
        int nt = b3 >> 3, kt = b3 & 7;
        src = wout; ld = 512; cb = nt * 64;
        dst = woutT + (size_t)(nt * 64) * 512;
        k0 = kt * 64;
    }

    {
        int r = tid >> 4, c4 = (tid & 15) * 4;
        #pragma unroll
        for (int p = 0; p < 4; ++p) {
            int rr = r + p * 16;
            float4 v = *reinterpret_cast<const float4*>(&src[(size_t)(k0 + rr) * ld + cb + c4]);
            tile[c4 + 0][rr] = f2bf(v.x);
            tile[c4 + 1][rr] = f2bf(v.y);
            tile[c4 + 2][rr] = f2bf(v.z);
            tile[c4 + 3][rr] = f2bf(v.w);
        }
    }
    __syncthreads();
    {
        int nl = tid >> 3, ks = (tid & 7) * 8;
        #pragma unroll
        for (int rep = 0; rep < 2; ++rep) {
            int nn = nl + rep * 32;
            ushort8v vv = *reinterpret_cast<const ushort8v*>(&tile[nn][ks]);
            *reinterpret_cast<ushort8v*>(&dst[(size_t)nn * 512 + k0 + ks]) = vv;
        }
    }
}

// ---------------------------------------------------------------------------
// bf16 MFMA GEMM, single-buffered (round-12 known-good), templated on BN.
// ---------------------------------------------------------------------------
template<int BM, int BN, bool F32OUT>
__global__ __launch_bounds__(256, 4) void gemm_k(
    const ushort_t* __restrict__ A,    // [MPAD][512] bf16
    const ushort_t* __restrict__ BT,   // [N][512] bf16
    const float* __restrict__ bias,
    void* __restrict__ Cv, int ldc)
{
    __shared__ ushort_t sA[BM * 64];
    __shared__ ushort_t sB[BN * 64];
    const int tid = threadIdx.x;

    const int nwg = gridDim.x * gridDim.y;
    const int orig = blockIdx.y * gridDim.x + blockIdx.x;
    const int xcd = orig & 7;
    const int qq = nwg >> 3, rr8 = nwg & 7;
    const int wg = (xcd < rr8 ? xcd * (qq + 1) : rr8 * (qq + 1) + (xcd - rr8) * qq)
                   + (orig >> 3);
    const int row0 = (wg / gridDim.x) * BM;
    const int col0 = (wg % gridDim.x) * BN;

    constexpr int NWC = BN / 64;       // wave-cols
    constexpr int NWR = 4 / NWC;       // wave-rows
    constexpr int WROWS = BM / NWR;    // rows per wave
    constexpr int MR = WROWS / 16;     // m-fragments per wave

    const int wid = tid >> 6, lane = tid & 63;
    const int wr = wid / NWC, wc = wid % NWC;
    const int l15 = lane & 15, kp = lane >> 4;

    floatx4 acc[MR][4];
    #pragma unroll
    for (int m = 0; m < MR; ++m)
        #pragma unroll
        for (int n = 0; n < 4; ++n)
            acc[m][n] = (floatx4){0.f, 0.f, 0.f, 0.f};

    const ushort_t* Abase = A + (size_t)row0 * 512;
    const ushort_t* Bbase = BT + (size_t)col0 * 512;

    for (int kt = 0; kt < 8; ++kt) {
        const int k0 = kt * 64;
        #pragma unroll
        for (int rnd = 0; rnd < BM / 32; ++rnd) {
            int r = rnd * 32 + (tid >> 3);
            int gs = (tid & 7) ^ (r & 7);
            __builtin_amdgcn_global_load_lds(
                (guint_t*)(Abase + (size_t)r * 512 + k0 + gs * 8),
                (luint_t*)(sA + r * 64 + (tid & 7) * 8), 16, 0, 0);
        }
        #pragma unroll
        for (int rnd = 0; rnd < BN / 32; ++rnd) {
            int r = rnd * 32 + (tid >> 3);
            int gs = (tid & 7) ^ (r & 7);
            __builtin_amdgcn_global_load_lds(
                (guint_t*)(Bbase + (size_t)r * 512 + k0 + gs * 8),
                (luint_t*)(sB + r * 64 + (tid & 7) * 8), 16, 0, 0);
        }
        __syncthreads();

        #pragma unroll
        for (int kk = 0; kk < 2; ++kk) {
            short8v af[MR], bfr[4];
            #pragma unroll
            for (int m = 0; m < MR; ++m) {
                int r = wr * WROWS + m * 16 + l15;
                int slot = kk * 4 + kp;
                af[m] = *(const short8v*)&sA[r * 64 + ((slot ^ (r & 7)) << 3)];
            }
            #pragma unroll
            for (int n = 0; n < 4; ++n) {
                int r = wc * 64 + n * 16 + l15;
                int slot = kk * 4 + kp;
                bfr[n] = *(const short8v*)&sB[r * 64 + ((slot ^ (r & 7)) << 3)];
            }
            #pragma unroll
            for (int m = 0; m < MR; ++m)
                #pragma unroll
                for (int n = 0; n < 4; ++n)
                    acc[m][n] = __builtin_amdgcn_mfma_f32_16x16x32_bf16(
                        af[m], bfr[n], acc[m][n], 0, 0, 0);
        }
        __syncthreads();
    }

    if (!F32OUT) {
        ushort_t* C = (ushort_t*)Cv;
        #pragma unroll
        for (int m = 0; m < MR; ++m) {
            int rb = row0 + wr * WROWS + m * 16 + kp * 4;
            #pragma unroll
            for (int n = 0; n < 4; ++n) {
                int col = col0 + wc * 64 + n * 16 + l15;
                #pragma unroll
                for (int q = 0; q < 4; ++q)
                    C[(size_t)(rb + q) * ldc + col] = f2bf(acc[m][n][q]);
            }
        }
    } else {
        float* C = (float*)Cv;
        #pragma unroll
        for (int m = 0; m < MR; ++m) {
            int rb = row0 + wr * WROWS + m * 16 + kp * 4;
            #pragma unroll
            for (int n = 0; n < 4; ++n) {
                int col = col0 + wc * 64 + n * 16 + l15;
                float bv = bias[col];
                #pragma unroll
                for (int q = 0; q < 4; ++q)
                    if (rb + q < NSEQ)
                        C[(size_t)(rb + q) * ldc + col] = acc[m][n][q] + bv;
            }
        }
    }
}

// ---------------------------------------------------------------------------
// Attention, wave-per-token (round-9/12 structure), inner math moved to
// PACKED fp32 (float2 + __builtin_elementwise_fma -> v_pk_fma_f32):
// per 8-elem row: 4 lshl + 4 and + 4 pk_fma (13 ops) vs 8 lshl + 8 fmac (16).
// Chunked batched K loads, V chunk-1 prefetch under softmax, hoisted PV
// broadcasts, __launch_bounds__(256,4), XCD-chunked block swizzle.
// ---------------------------------------------------------------------------
__global__ __launch_bounds__(256, 4) void attn_k(
    const ushort_t* __restrict__ qkv,
    const float* __restrict__ wtalk,
    ushort_t* __restrict__ outh)
{
    const int lane = threadIdx.x & 63;
    const int bid0 = blockIdx.x;                            // 1152 = 8*144
    const int bswz = (bid0 & 7) * (gridDim.x >> 3) + (bid0 >> 3);
    const int i = bswz * 4 + (threadIdx.x >> 6);
    const int h = lane >> 3, s = lane & 7;

    const int t = i / (H_ * W_), rem = i % (H_ * W_);
    const int yy = rem / W_, xx = rem % W_;

    int rowj = -1;
    if (lane == 0) rowj = 0;
    else if (lane < NNB) {
        int e = lane - 1;
        int dt = e / 9 - 1, dy = (e / 3) % 3 - 1, dx = e % 3 - 1;
        int nt = t + dt, ny = yy + dy, nx = xx + dx;
        bool valid = ((unsigned)nt < (unsigned)F_) && ((unsigned)ny < (unsigned)H_) &&
                     ((unsigned)nx < (unsigned)W_);
        int u = (nt * H_ + ny) * W_ + nx;
        rowj = (valid && u <= i) ? (u + 1) : -1;
    }

    // clamped row table for loads (masked -> row 0)
    int rows[NNB];
    #pragma unroll
    for (int j = 0; j < NNB; ++j) {
        int r = __shfl(rowj, j, 64);
        rows[j] = r < 0 ? 0 : r;
    }

    // q as 4 packed float2 pairs
    floatx2 qf2[4];
    {
        uint4v qv = *(const uint4v*)&qkv[(size_t)(i + 1) * QKVC + lane * 8];
        #pragma unroll
        for (int p = 0; p < 4; ++p) qf2[p] = up2(qv[p]);
    }

    // ---- K dots, chunked 12/12/4 (batched loads, packed fma) ----
    float ps[NNB];
    {
        uint4v kc[12];
        #pragma unroll
        for (int j = 0; j < 12; ++j)
            kc[j] = *(const uint4v*)&qkv[(size_t)rows[j] * QKVC + 512 + lane * 8];
        #pragma unroll
        for (int j = 0; j < 12; ++j) {
            floatx2 a2 = (floatx2){0.f, 0.f};
            #pragma unroll
            for (int p = 0; p < 4; ++p)
                a2 = __builtin_elementwise_fma(qf2[p], up2(kc[j][p]), a2);
            ps[j] = a2.x + a2.y;
        }
        #pragma unroll
        for (int j = 12; j < 24; ++j)
            kc[j - 12] = *(const uint4v*)&qkv[(size_t)rows[j] * QKVC + 512 + lane * 8];
        #pragma unroll
        for (int j = 12; j < 24; ++j) {
            floatx2 a2 = (floatx2){0.f, 0.f};
            #pragma unroll
            for (int p = 0; p < 4; ++p)
                a2 = __builtin_elementwise_fma(qf2[p], up2(kc[j - 12][p]), a2);
            ps[j] = a2.x + a2.y;
        }
        uint4v kt_[4];
        #pragma unroll
        for (int j = 24; j < 28; ++j)
            kt_[j - 24] = *(const uint4v*)&qkv[(size_t)rows[j] * QKVC + 512 + lane * 8];
        #pragma unroll
        for (int j = 24; j < 28; ++j) {
            floatx2 a2 = (floatx2){0.f, 0.f};
            #pragma unroll
            for (int p = 0; p < 4; ++p)
                a2 = __builtin_elementwise_fma(qf2[p], up2(kt_[j - 24][p]), a2);
            ps[j] = a2.x + a2.y;
        }
    }

    // ---- V chunk-1 prefetch: in flight across reduce/softmax/TH ----
    uint4v vc[12];
    #pragma unroll
    for (int j = 0; j < 12; ++j)
        vc[j] = *(const uint4v*)&qkv[(size_t)rows[j] * QKVC + 1024 + lane * 8];

    // ---- reduce-scatter (xor 1,2,4) ----
    float v1[14];
    {
        bool hi = (s & 1) != 0;
        #pragma unroll
        for (int m = 0; m < 14; ++m) {
            float keep = hi ? ps[2 * m + 1] : ps[2 * m];
            float oth  = hi ? ps[2 * m]     : ps[2 * m + 1];
            v1[m] = keep + __shfl_xor(oth, 1, 64);
        }
    }
    float v2[8];
    {
        bool hi = (s & 2) != 0;
        #pragma unroll
        for (int m = 0; m < 7; ++m) {
            float keep = hi ? v1[2 * m + 1] : v1[2 * m];
            float oth  = hi ? v1[2 * m]     : v1[2 * m + 1];
            v2[m] = keep + __shfl_xor(oth, 2, 64);
        }
        v2[7] = 0.f;
    }
    float simk[4];
    {
        bool hi = (s & 4) != 0;
        #pragma unroll
        for (int k = 0; k < 4; ++k) {
            float keep = hi ? v2[2 * k + 1] : v2[2 * k];
            float oth  = hi ? v2[2 * k]     : v2[2 * k + 1];
            simk[k] = keep + __shfl_xor(oth, 4, 64);
        }
    }
    #pragma unroll
    for (int k = 0; k < 4; ++k) {
        int j = s + 8 * k;
        int rj = __shfl(rowj, j, 64);
        simk[k] = (rj >= 0) ? simk[k] * SCALEF : -FLT_MAX;
    }

    // ---- softmax over the 8-lane x 4-slot group ----
    float mx = fmaxf(fmaxf(simk[0], simk[1]), fmaxf(simk[2], simk[3]));
    mx = fmaxf(mx, __shfl_xor(mx, 1, 64));
    mx = fmaxf(mx, __shfl_xor(mx, 2, 64));
    mx = fmaxf(mx, __shfl_xor(mx, 4, 64));
    float att[4];
    float S = 0.f;
    #pragma unroll
    for (int k = 0; k < 4; ++k) { att[k] = __expf(simk[k] - mx); S += att[k]; }
    S += __shfl_xor(S, 1, 64);
    S += __shfl_xor(S, 2, 64);
    S += __shfl_xor(S, 4, 64);
    float inv = 1.f / S;
    #pragma unroll
    for (int k = 0; k < 4; ++k) att[k] *= inv;

    // ---- talking heads ----
    float wtg[8];
    #pragma unroll
    for (int hh = 0; hh < 8; ++hh) wtg[hh] = wtalk[h * 8 + hh];
    float pk[4];
    #pragma unroll
    for (int k = 0; k < 4; ++k) {
        float acc = 0.f;
        #pragma unroll
        for (int hh = 0; hh < 8; ++hh)
            acc += wtg[hh] * __shfl(att[k], hh * 8 + s, 64);
        pk[k] = acc;
    }

    // hoisted PV broadcasts (as packed pairs)
    floatx2 pj2[NNB];
    #pragma unroll
    for (int j = 0; j < NNB; ++j) {
        float pj = __shfl(pk[j >> 3], h * 8 + (j & 7), 64);
        pj2[j] = (floatx2){pj, pj};
    }

    // ---- PV, chunked 12/12/4 (packed fma) ----
    floatx2 o2[4];
    #pragma unroll
    for (int p = 0; p < 4; ++p) o2[p] = (floatx2){0.f, 0.f};
    #pragma unroll
    for (int j = 0; j < 12; ++j) {
        #pragma unroll
        for (int p = 0; p < 4; ++p)
            o2[p] = __builtin_elementwise_fma(pj2[j], up2(vc[j][p]), o2[p]);
    }
    #pragma unroll
    for (int j = 12; j < 24; ++j)
        vc[j - 12] = *(const uint4v*)&qkv[(size_t)rows[j] * QKVC + 1024 + lane * 8];
    #pragma unroll
    for (int j = 12; j < 24; ++j) {
        #pragma unroll
        for (int p = 0; p < 4; ++p)
            o2[p] = __builtin_elementwise_fma(pj2[j], up2(vc[j - 12][p]), o2[p]);
    }
    {
        uint4v vt_[4];
        #pragma unroll
        for (int j = 24; j < 28; ++j)
            vt_[j - 24] = *(const uint4v*)&qkv[(size_t)rows[j] * QKVC + 1024 + lane * 8];
        #pragma unroll
        for (int j = 24; j < 28; ++j) {
            #pragma unroll
            for (int p = 0; p < 4; ++p)
                o2[p] = __builtin_elementwise_fma(pj2[j], up2(vt_[j - 24][p]), o2[p]);
        }
    }

    ushort8v ov;
    #pragma unroll
    for (int p = 0; p < 4; ++p) {
        ov[2 * p]     = f2bf(o2[p].x);
        ov[2 * p + 1] = f2bf(o2[p].y);
    }
    *(ushort8v*)&outh[(size_t)(i + 1) * DIM + lane * 8] = ov;

    if (i == 0) {
        ushort8v bv = *(const ushort8v*)&qkv[1024 + lane * 8];
        *(ushort8v*)&outh[lane * 8] = bv;
    }
}

extern "C" void kernel_launch(void* const* d_in, const int* in_sizes, int n_in,
                              void* d_out, int out_size, void* d_ws, size_t ws_size,
                              hipStream_t stream) {
    const float* x     = (const float*)d_in[0];
    const float* wq    = (const float*)d_in[1];
    const float* wkv   = (const float*)d_in[2];
    const float* wtalk = (const float*)d_in[3];
    const float* wout  = (const float*)d_in[4];
    const float* bout  = (const float*)d_in[5];
    float* out = (float*)d_out;

    ushort_t* xb    = (ushort_t*)d_ws;                    // MPAD*512 bf16
    ushort_t* wcatT = xb    + (size_t)MPAD * 512;         // 1536*512
    ushort_t* woutT = wcatT + (size_t)QKVC * 512;         // 512*512
    ushort_t* qkv   = woutT + (size_t)512 * 512;          // MPAD*1536
    ushort_t* outh  = qkv   + (size_t)MPAD * QKVC;        // MPAD*512

    dim3 blk(256);
    conv_k<<<CONV_BLOCKS, blk, 0, stream>>>(x, wq, wkv, wout, xb, wcatT, woutT);
    gemm_k<64, 128, false><<<dim3(12, 74), blk, 0, stream>>>(xb, wcatT, nullptr, qkv, QKVC);
    attn_k<<<dim3(NTOK / 4), blk, 0, stream>>>(qkv, wtalk, outh);
    gemm_k<64, 64, true><<<dim3(8, 74), blk, 0, stream>>>(outh, woutT, bout, out, DIM);
}